// Round 2
// baseline (546.930 us; speedup 1.0000x reference)
//
#include <hip/hip_runtime.h>
#include <math.h>

#define NEIGHBORHOOD 2
#define EPS_NORM 1e-8f
#define EPS_DEN 1e-6f

// ---------------------------------------------------------------------------
// Kernel A: per-row inverse norm.  One 64-lane wave per (b,t) row, C=512.
// Lane l loads float4 at c=l*4 and c=256+l*4 (fully coalesced).
// ---------------------------------------------------------------------------
__global__ void invnorm_kernel(const float* __restrict__ x,
                               float* __restrict__ invn, int C) {
    const int row  = blockIdx.x;
    const int lane = threadIdx.x;  // 0..63
    const float* xr = x + (size_t)row * C;

    float4 a = *reinterpret_cast<const float4*>(xr + lane * 4);
    float4 b = *reinterpret_cast<const float4*>(xr + 256 + lane * 4);
    float ss = a.x * a.x + a.y * a.y + a.z * a.z + a.w * a.w
             + b.x * b.x + b.y * b.y + b.z * b.z + b.w * b.w;

    #pragma unroll
    for (int off = 32; off > 0; off >>= 1)
        ss += __shfl_down(ss, off, 64);

    if (lane == 0)
        invn[row] = 1.0f / fmaxf(sqrtf(ss), EPS_NORM);
}

// ---------------------------------------------------------------------------
// Kernel B: banded masked similarity sum.  One wave per (b,t).
// regions sorted ascending per batch, so valid s form the contiguous run
// s in (t, T) with r_s <= r_t + NEIGHBORHOOD.  padding: r_t==0 kills the row
// (r_s >= r_t so r_s==0 implies r_t==0).
// Accumulate y[c] = sum_s sign_s*invn_s*x_s[c], then one dot with x_t.
// ---------------------------------------------------------------------------
__global__ void band_kernel(const float* __restrict__ x,
                            const int* __restrict__ regions,
                            const float* __restrict__ invn,
                            float* __restrict__ accum,  // [0]=sum, [1]=count
                            int T, int C) {
    const int b    = blockIdx.y;
    const int t    = blockIdx.x;
    const int lane = threadIdx.x;  // 0..63

    const int* reg = regions + (size_t)b * T;
    const int rt = reg[t];
    if (rt == 0) return;  // padding row: every pair excluded

    const float* xb   = x    + ((size_t)b * T) * C;
    const float* invb = invn + (size_t)b * T;

    float4 acc0 = make_float4(0.f, 0.f, 0.f, 0.f);
    float4 acc1 = make_float4(0.f, 0.f, 0.f, 0.f);
    int cnt = 0;

    const int rmax = rt + NEIGHBORHOOD;
    for (int s = t + 1; s < T; ++s) {
        const int rs = reg[s];
        if (rs > rmax) break;  // sorted: no further s qualifies
        const float w = ((rs == rt) ? 1.0f : -1.0f) * invb[s];
        const float* xs = xb + (size_t)s * C;
        float4 v0 = *reinterpret_cast<const float4*>(xs + lane * 4);
        float4 v1 = *reinterpret_cast<const float4*>(xs + 256 + lane * 4);
        acc0.x = fmaf(w, v0.x, acc0.x);
        acc0.y = fmaf(w, v0.y, acc0.y);
        acc0.z = fmaf(w, v0.z, acc0.z);
        acc0.w = fmaf(w, v0.w, acc0.w);
        acc1.x = fmaf(w, v1.x, acc1.x);
        acc1.y = fmaf(w, v1.y, acc1.y);
        acc1.z = fmaf(w, v1.z, acc1.z);
        acc1.w = fmaf(w, v1.w, acc1.w);
        ++cnt;
    }
    if (cnt == 0) return;  // cnt is wave-uniform

    const float* xt = xb + (size_t)t * C;
    float4 t0 = *reinterpret_cast<const float4*>(xt + lane * 4);
    float4 t1 = *reinterpret_cast<const float4*>(xt + 256 + lane * 4);
    float dot = t0.x * acc0.x + t0.y * acc0.y + t0.z * acc0.z + t0.w * acc0.w
              + t1.x * acc1.x + t1.y * acc1.y + t1.z * acc1.z + t1.w * acc1.w;

    #pragma unroll
    for (int off = 32; off > 0; off >>= 1)
        dot += __shfl_down(dot, off, 64);

    if (lane == 0) {
        atomicAdd(&accum[0], dot * invb[t]);
        atomicAdd(&accum[1], (float)cnt);
    }
}

// ---------------------------------------------------------------------------
// Kernel C: loss = 1 - sum / (count + eps)
// ---------------------------------------------------------------------------
__global__ void finalize_kernel(const float* __restrict__ accum,
                                float* __restrict__ out) {
    out[0] = 1.0f - accum[0] / (accum[1] + EPS_DEN);
}

extern "C" void kernel_launch(void* const* d_in, const int* in_sizes, int n_in,
                              void* d_out, int out_size, void* d_ws, size_t ws_size,
                              hipStream_t stream) {
    const float* x       = (const float*)d_in[0];
    const int*   regions = (const int*)d_in[1];

    const int BT = in_sizes[1];              // B*T
    const int C  = in_sizes[0] / BT;         // 512
    const int T  = 2048;                     // per reference setup
    const int B  = BT / T;                   // 8

    // workspace layout: [0..1] float accumulators (16B-aligned pad), then invn[BT]
    float* accum = (float*)d_ws;
    float* invn  = (float*)d_ws + 4;

    hipMemsetAsync(accum, 0, 2 * sizeof(float), stream);

    invnorm_kernel<<<BT, 64, 0, stream>>>(x, invn, C);

    dim3 grid(T, B);
    band_kernel<<<grid, 64, 0, stream>>>(x, regions, invn, accum, T, C);

    finalize_kernel<<<1, 1, 0, stream>>>(accum, (float*)d_out);
}

// Round 4
// 117.211 us; speedup vs baseline: 4.6662x; 4.6662x over previous
//
#include <hip/hip_runtime.h>
#include <math.h>

#define NEIGHBORHOOD 2
#define EPS_NORM 1e-8f
#define EPS_DEN 1e-6f
#define NVAL 128   // region values are in [0, 128)

// ---------------------------------------------------------------------------
// Kernel A: per-row inverse norm.  One 64-lane wave per (b,t) row, C=512.
// ---------------------------------------------------------------------------
__global__ void invnorm_kernel(const float* __restrict__ x,
                               float* __restrict__ invn, int C) {
    const int row  = blockIdx.x;
    const int lane = threadIdx.x;  // 0..63
    const float* xr = x + (size_t)row * C;

    float4 a = *reinterpret_cast<const float4*>(xr + lane * 4);
    float4 b = *reinterpret_cast<const float4*>(xr + 256 + lane * 4);
    float ss = a.x * a.x + a.y * a.y + a.z * a.z + a.w * a.w
             + b.x * b.x + b.y * b.y + b.z * b.z + b.w * b.w;

    #pragma unroll
    for (int off = 32; off > 0; off >>= 1)
        ss += __shfl_down(ss, off, 64);

    if (lane == 0)
        invn[row] = 1.0f / fmaxf(sqrtf(ss), EPS_NORM);
}

// ---------------------------------------------------------------------------
// Kernel B: per-run (batch b, region value v) sum of normalized rows.
// regions sorted ascending per batch -> value v occupies contiguous [lo, hi).
// Block = 256 threads; thread handles 2 channels (float2).  Fixed loop count
// after binary search -> loads pipeline (no data-dependent break).
// Writes S[b][v][:] (zeros if run empty) and n[b][v].
// ---------------------------------------------------------------------------
__global__ void runsum_kernel(const float* __restrict__ x,
                              const int* __restrict__ regions,
                              const float* __restrict__ invn,
                              float* __restrict__ S,   // [B][NVAL][C]
                              int* __restrict__ ncnt,  // [B][NVAL]
                              int T, int C) {
    const int v   = blockIdx.x;   // 0..127
    const int b   = blockIdx.y;
    const int tid = threadIdx.x;  // 0..255

    const int* reg = regions + (size_t)b * T;

    // lower_bound(v)
    int lo = 0, hi = T;
    while (lo < hi) { int m = (lo + hi) >> 1; if (reg[m] < v) lo = m + 1; else hi = m; }
    // lower_bound(v+1)
    int lo2 = lo, hi2 = T;
    while (lo2 < hi2) { int m = (lo2 + hi2) >> 1; if (reg[m] < v + 1) lo2 = m + 1; else hi2 = m; }

    const float* xb   = x    + ((size_t)b * T) * C;
    const float* invb = invn + (size_t)b * T;

    float2 acc = make_float2(0.f, 0.f);
    for (int t = lo; t < lo2; ++t) {
        const float w = invb[t];
        float2 vv = *reinterpret_cast<const float2*>(xb + (size_t)t * C + tid * 2);
        acc.x = fmaf(w, vv.x, acc.x);
        acc.y = fmaf(w, vv.y, acc.y);
    }

    float* Srow = S + ((size_t)b * NVAL + v) * C;
    *reinterpret_cast<float2*>(Srow + tid * 2) = acc;
    if (tid == 0) ncnt[b * NVAL + v] = lo2 - lo;
}

// ---------------------------------------------------------------------------
// Kernel C: per (b, v>=1) contribution.
//   contrib = (|S_v|^2 - n_v)/2 - S_v . (S_{v+1} + S_{v+2})
//   cnt     = n_v(n_v-1)/2 + n_v (n_{v+1} + n_{v+2})
// One wave per (b,v).  v+1/v+2 beyond 127 treated as empty.
// ---------------------------------------------------------------------------
__global__ void pairsum_kernel(const float* __restrict__ S,
                               const int* __restrict__ ncnt,
                               float* __restrict__ accum,  // [0]=sum,[1]=count
                               int C) {
    const int v    = blockIdx.x + 1;  // 1..127
    const int b    = blockIdx.y;
    const int lane = threadIdx.x;     // 0..63

    const float* Sv = S + ((size_t)b * NVAL + v) * C;

    float4 a0 = *reinterpret_cast<const float4*>(Sv + lane * 4);
    float4 a1 = *reinterpret_cast<const float4*>(Sv + 256 + lane * 4);

    float4 w0 = make_float4(0.f, 0.f, 0.f, 0.f);
    float4 w1 = make_float4(0.f, 0.f, 0.f, 0.f);
    int n1 = 0, n2 = 0;
    if (v + 1 < NVAL) {
        const float* S1 = Sv + C;
        float4 b0 = *reinterpret_cast<const float4*>(S1 + lane * 4);
        float4 b1 = *reinterpret_cast<const float4*>(S1 + 256 + lane * 4);
        w0.x += b0.x; w0.y += b0.y; w0.z += b0.z; w0.w += b0.w;
        w1.x += b1.x; w1.y += b1.y; w1.z += b1.z; w1.w += b1.w;
        n1 = ncnt[b * NVAL + v + 1];
    }
    if (v + 2 < NVAL) {
        const float* S2 = Sv + 2 * C;
        float4 b0 = *reinterpret_cast<const float4*>(S2 + lane * 4);
        float4 b1 = *reinterpret_cast<const float4*>(S2 + 256 + lane * 4);
        w0.x += b0.x; w0.y += b0.y; w0.z += b0.z; w0.w += b0.w;
        w1.x += b1.x; w1.y += b1.y; w1.z += b1.z; w1.w += b1.w;
        n2 = ncnt[b * NVAL + v + 2];
    }

    // partial of 0.5*|S_v|^2 - S_v.(S_{v+1}+S_{v+2})
    float part =
        0.5f * (a0.x*a0.x + a0.y*a0.y + a0.z*a0.z + a0.w*a0.w
              + a1.x*a1.x + a1.y*a1.y + a1.z*a1.z + a1.w*a1.w)
      - (a0.x*w0.x + a0.y*w0.y + a0.z*w0.z + a0.w*w0.w
       + a1.x*w1.x + a1.y*w1.y + a1.z*w1.z + a1.w*w1.w);

    #pragma unroll
    for (int off = 32; off > 0; off >>= 1)
        part += __shfl_down(part, off, 64);

    if (lane == 0) {
        const int nv = ncnt[b * NVAL + v];
        const float contrib = part - 0.5f * (float)nv;
        const float cnt = 0.5f * (float)(nv * (nv - 1)) + (float)(nv * (n1 + n2));
        atomicAdd(&accum[0], contrib);
        atomicAdd(&accum[1], cnt);
    }
}

// ---------------------------------------------------------------------------
// Kernel D: loss = 1 - sum / (count + eps)
// ---------------------------------------------------------------------------
__global__ void finalize_kernel(const float* __restrict__ accum,
                                float* __restrict__ out) {
    out[0] = 1.0f - accum[0] / (accum[1] + EPS_DEN);
}

extern "C" void kernel_launch(void* const* d_in, const int* in_sizes, int n_in,
                              void* d_out, int out_size, void* d_ws, size_t ws_size,
                              hipStream_t stream) {
    const float* x       = (const float*)d_in[0];
    const int*   regions = (const int*)d_in[1];

    const int BT = in_sizes[1];              // B*T = 16384
    const int C  = in_sizes[0] / BT;         // 512
    const int T  = 2048;                     // per reference setup
    const int B  = BT / T;                   // 8

    // workspace layout (float units):
    //   [0..15]              accum (uses 2) + pad
    //   [16 .. 16+BT)        invn
    //   [16+BT .. +B*NVAL)   ncnt (int)
    //   [16+BT+B*NVAL .. )   S  (B*NVAL*C floats), 16B-aligned
    float* base  = (float*)d_ws;
    float* accum = base;
    float* invn  = base + 16;
    int*   ncnt  = (int*)(base + 16 + BT);
    float* S     = base + 16 + BT + B * NVAL;

    hipMemsetAsync(accum, 0, 2 * sizeof(float), stream);

    invnorm_kernel<<<BT, 64, 0, stream>>>(x, invn, C);

    runsum_kernel<<<dim3(NVAL, B), 256, 0, stream>>>(x, regions, invn, S, ncnt, T, C);

    pairsum_kernel<<<dim3(NVAL - 1, B), 64, 0, stream>>>(S, ncnt, accum, C);

    finalize_kernel<<<1, 1, 0, stream>>>(accum, (float*)d_out);
}

// Round 5
// 106.968 us; speedup vs baseline: 5.1130x; 1.0958x over previous
//
#include <hip/hip_runtime.h>
#include <math.h>

#define NEIGHBORHOOD 2
#define EPS_NORM 1e-8f
#define EPS_DEN 1e-6f
#define NVAL 128   // region values are in [0, 128)

// ---------------------------------------------------------------------------
// Kernel 1: fused per-run normalized-row sum.
// Block = (region value v, batch b), 256 threads = 4 waves.
// regions sorted ascending per batch -> value v occupies contiguous [lo, lo2).
// Wave w handles rows t = lo+w, lo+w+4, ...  For each row: compute the norm
// in-register (float4 x2 per lane, shfl_xor reduce so all lanes get it),
// then FMA x_t/||x_t|| into per-wave channel accumulators.  4 waves combine
// via 8 KB LDS.  Writes S[b][v][:] and ncnt[b][v].
// Block (0,0) additionally zeroes accum[0..1] (safe: kernel boundary orders
// it before pairsum's atomics).  v==0 runs are padding -> never consumed.
// ---------------------------------------------------------------------------
__global__ void fused_runsum_kernel(const float* __restrict__ x,
                                    const int* __restrict__ regions,
                                    float* __restrict__ S,   // [B][NVAL][C]
                                    int* __restrict__ ncnt,  // [B][NVAL]
                                    float* __restrict__ accum,
                                    int T, int C) {
    const int v    = blockIdx.x;   // 0..127
    const int b    = blockIdx.y;
    const int tid  = threadIdx.x;  // 0..255
    const int wid  = tid >> 6;     // wave 0..3
    const int lane = tid & 63;

    if (v == 0) {                  // padding value: S_0 / n_0 never read
        if (b == 0 && tid == 0) { accum[0] = 0.f; accum[1] = 0.f; }
        return;
    }

    const int* reg = regions + (size_t)b * T;

    // lower_bound(v)
    int lo = 0, hi = T;
    while (lo < hi) { int m = (lo + hi) >> 1; if (reg[m] < v) lo = m + 1; else hi = m; }
    // lower_bound(v+1)
    int lo2 = lo, hi2 = T;
    while (lo2 < hi2) { int m = (lo2 + hi2) >> 1; if (reg[m] < v + 1) lo2 = m + 1; else hi2 = m; }

    const float* xb = x + ((size_t)b * T) * C;

    float4 acc0 = make_float4(0.f, 0.f, 0.f, 0.f);
    float4 acc1 = make_float4(0.f, 0.f, 0.f, 0.f);

    for (int t = lo + wid; t < lo2; t += 4) {
        const float* xr = xb + (size_t)t * C;
        float4 a = *reinterpret_cast<const float4*>(xr + lane * 4);
        float4 c = *reinterpret_cast<const float4*>(xr + 256 + lane * 4);
        float ss = a.x*a.x + a.y*a.y + a.z*a.z + a.w*a.w
                 + c.x*c.x + c.y*c.y + c.z*c.z + c.w*c.w;
        #pragma unroll
        for (int off = 32; off > 0; off >>= 1)
            ss += __shfl_xor(ss, off, 64);          // all lanes get the sum
        const float w = 1.0f / fmaxf(sqrtf(ss), EPS_NORM);
        acc0.x = fmaf(w, a.x, acc0.x);
        acc0.y = fmaf(w, a.y, acc0.y);
        acc0.z = fmaf(w, a.z, acc0.z);
        acc0.w = fmaf(w, a.w, acc0.w);
        acc1.x = fmaf(w, c.x, acc1.x);
        acc1.y = fmaf(w, c.y, acc1.y);
        acc1.z = fmaf(w, c.z, acc1.z);
        acc1.w = fmaf(w, c.w, acc1.w);
    }

    // combine the 4 waves' 512-channel accumulators via LDS
    __shared__ float sm[4][512];
    *reinterpret_cast<float4*>(&sm[wid][lane * 4])       = acc0;
    *reinterpret_cast<float4*>(&sm[wid][256 + lane * 4]) = acc1;
    __syncthreads();

    // 256 threads, 2 channels each
    const int ch = tid * 2;
    float2 r;
    r.x = sm[0][ch]     + sm[1][ch]     + sm[2][ch]     + sm[3][ch];
    r.y = sm[0][ch + 1] + sm[1][ch + 1] + sm[2][ch + 1] + sm[3][ch + 1];

    float* Srow = S + ((size_t)b * NVAL + v) * C;
    *reinterpret_cast<float2*>(Srow + ch) = r;
    if (tid == 0) ncnt[b * NVAL + v] = lo2 - lo;
}

// ---------------------------------------------------------------------------
// Kernel 2: per (b, v>=1) contribution.
//   contrib = (|S_v|^2 - n_v)/2 - S_v . (S_{v+1} + S_{v+2})
//   cnt     = n_v(n_v-1)/2 + n_v (n_{v+1} + n_{v+2})
// One wave per (b,v).  v+1/v+2 beyond 127 treated as empty.
// ---------------------------------------------------------------------------
__global__ void pairsum_kernel(const float* __restrict__ S,
                               const int* __restrict__ ncnt,
                               float* __restrict__ accum,  // [0]=sum,[1]=count
                               int C) {
    const int v    = blockIdx.x + 1;  // 1..127
    const int b    = blockIdx.y;
    const int lane = threadIdx.x;     // 0..63

    const float* Sv = S + ((size_t)b * NVAL + v) * C;

    float4 a0 = *reinterpret_cast<const float4*>(Sv + lane * 4);
    float4 a1 = *reinterpret_cast<const float4*>(Sv + 256 + lane * 4);

    float4 w0 = make_float4(0.f, 0.f, 0.f, 0.f);
    float4 w1 = make_float4(0.f, 0.f, 0.f, 0.f);
    int n1 = 0, n2 = 0;
    if (v + 1 < NVAL) {
        const float* S1 = Sv + C;
        float4 b0 = *reinterpret_cast<const float4*>(S1 + lane * 4);
        float4 b1 = *reinterpret_cast<const float4*>(S1 + 256 + lane * 4);
        w0.x += b0.x; w0.y += b0.y; w0.z += b0.z; w0.w += b0.w;
        w1.x += b1.x; w1.y += b1.y; w1.z += b1.z; w1.w += b1.w;
        n1 = ncnt[b * NVAL + v + 1];
    }
    if (v + 2 < NVAL) {
        const float* S2 = Sv + 2 * C;
        float4 b0 = *reinterpret_cast<const float4*>(S2 + lane * 4);
        float4 b1 = *reinterpret_cast<const float4*>(S2 + 256 + lane * 4);
        w0.x += b0.x; w0.y += b0.y; w0.z += b0.z; w0.w += b0.w;
        w1.x += b1.x; w1.y += b1.y; w1.z += b1.z; w1.w += b1.w;
        n2 = ncnt[b * NVAL + v + 2];
    }

    float part =
        0.5f * (a0.x*a0.x + a0.y*a0.y + a0.z*a0.z + a0.w*a0.w
              + a1.x*a1.x + a1.y*a1.y + a1.z*a1.z + a1.w*a1.w)
      - (a0.x*w0.x + a0.y*w0.y + a0.z*w0.z + a0.w*w0.w
       + a1.x*w1.x + a1.y*w1.y + a1.z*w1.z + a1.w*w1.w);

    #pragma unroll
    for (int off = 32; off > 0; off >>= 1)
        part += __shfl_down(part, off, 64);

    if (lane == 0) {
        const int nv = ncnt[b * NVAL + v];
        const float contrib = part - 0.5f * (float)nv;
        const float cnt = 0.5f * (float)(nv * (nv - 1)) + (float)(nv * (n1 + n2));
        atomicAdd(&accum[0], contrib);
        atomicAdd(&accum[1], cnt);
    }
}

// ---------------------------------------------------------------------------
// Kernel 3: loss = 1 - sum / (count + eps)
// ---------------------------------------------------------------------------
__global__ void finalize_kernel(const float* __restrict__ accum,
                                float* __restrict__ out) {
    out[0] = 1.0f - accum[0] / (accum[1] + EPS_DEN);
}

extern "C" void kernel_launch(void* const* d_in, const int* in_sizes, int n_in,
                              void* d_out, int out_size, void* d_ws, size_t ws_size,
                              hipStream_t stream) {
    const float* x       = (const float*)d_in[0];
    const int*   regions = (const int*)d_in[1];

    const int BT = in_sizes[1];              // B*T = 16384
    const int C  = in_sizes[0] / BT;         // 512
    const int T  = 2048;                     // per reference setup
    const int B  = BT / T;                   // 8

    // workspace layout (float units):
    //   [0..15]            accum (uses 2) + pad
    //   [16 .. 16+B*NVAL)  ncnt (int)
    //   [16+B*NVAL .. )    S  (B*NVAL*C floats), 16B-aligned
    float* base  = (float*)d_ws;
    float* accum = base;
    int*   ncnt  = (int*)(base + 16);
    float* S     = base + 16 + B * NVAL;

    fused_runsum_kernel<<<dim3(NVAL, B), 256, 0, stream>>>(x, regions, S, ncnt,
                                                           accum, T, C);

    pairsum_kernel<<<dim3(NVAL - 1, B), 64, 0, stream>>>(S, ncnt, accum, C);

    finalize_kernel<<<1, 1, 0, stream>>>(accum, (float*)d_out);
}

// Round 7
// 84.311 us; speedup vs baseline: 6.4871x; 1.2687x over previous
//
#include <hip/hip_runtime.h>
#include <math.h>

#define NEIGHBORHOOD 2
#define EPS_NORM 1e-8f
#define EPS_DEN 1e-6f
#define NVAL 128   // region values are in [0, 128)

// ---------------------------------------------------------------------------
// Kernel 1: fused per-run normalized-row sum.
// Block = (region value v, batch b), 256 threads = 4 waves.
// regions sorted ascending per batch -> value v occupies contiguous [lo, lo2).
// Wave w handles rows t = lo+w, lo+w+4, ...  For each row: compute the norm
// in-register (float4 x2 per lane, shfl_xor reduce so all lanes get it),
// then FMA x_t/||x_t|| into per-wave channel accumulators.  4 waves combine
// via 8 KB LDS.  Writes S[b][v][:] and ncnt[b][v].
// Block (0,0) zeroes accum + done-counter (kernel boundary orders this
// before kernel 2's atomics).  v==0 runs are padding -> never consumed.
// ---------------------------------------------------------------------------
__global__ void fused_runsum_kernel(const float* __restrict__ x,
                                    const int* __restrict__ regions,
                                    float* __restrict__ S,   // [B][NVAL][C]
                                    int* __restrict__ ncnt,  // [B][NVAL]
                                    float* __restrict__ accum,
                                    int* __restrict__ counter,
                                    int T, int C) {
    const int v    = blockIdx.x;   // 0..127
    const int b    = blockIdx.y;
    const int tid  = threadIdx.x;  // 0..255
    const int wid  = tid >> 6;     // wave 0..3
    const int lane = tid & 63;

    if (v == 0) {                  // padding value: S_0 / n_0 never read
        if (b == 0 && tid == 0) { accum[0] = 0.f; accum[1] = 0.f; *counter = 0; }
        return;
    }

    const int* reg = regions + (size_t)b * T;

    // lower_bound(v)
    int lo = 0, hi = T;
    while (lo < hi) { int m = (lo + hi) >> 1; if (reg[m] < v) lo = m + 1; else hi = m; }
    // lower_bound(v+1)
    int lo2 = lo, hi2 = T;
    while (lo2 < hi2) { int m = (lo2 + hi2) >> 1; if (reg[m] < v + 1) lo2 = m + 1; else hi2 = m; }

    const float* xb = x + ((size_t)b * T) * C;

    float4 acc0 = make_float4(0.f, 0.f, 0.f, 0.f);
    float4 acc1 = make_float4(0.f, 0.f, 0.f, 0.f);

    for (int t = lo + wid; t < lo2; t += 4) {
        const float* xr = xb + (size_t)t * C;
        float4 a = *reinterpret_cast<const float4*>(xr + lane * 4);
        float4 c = *reinterpret_cast<const float4*>(xr + 256 + lane * 4);
        float ss = a.x*a.x + a.y*a.y + a.z*a.z + a.w*a.w
                 + c.x*c.x + c.y*c.y + c.z*c.z + c.w*c.w;
        #pragma unroll
        for (int off = 32; off > 0; off >>= 1)
            ss += __shfl_xor(ss, off, 64);          // all lanes get the sum
        const float w = 1.0f / fmaxf(sqrtf(ss), EPS_NORM);
        acc0.x = fmaf(w, a.x, acc0.x);
        acc0.y = fmaf(w, a.y, acc0.y);
        acc0.z = fmaf(w, a.z, acc0.z);
        acc0.w = fmaf(w, a.w, acc0.w);
        acc1.x = fmaf(w, c.x, acc1.x);
        acc1.y = fmaf(w, c.y, acc1.y);
        acc1.z = fmaf(w, c.z, acc1.z);
        acc1.w = fmaf(w, c.w, acc1.w);
    }

    // combine the 4 waves' 512-channel accumulators via LDS
    __shared__ float sm[4][512];
    *reinterpret_cast<float4*>(&sm[wid][lane * 4])       = acc0;
    *reinterpret_cast<float4*>(&sm[wid][256 + lane * 4]) = acc1;
    __syncthreads();

    const int ch = tid * 2;
    float2 r;
    r.x = sm[0][ch]     + sm[1][ch]     + sm[2][ch]     + sm[3][ch];
    r.y = sm[0][ch + 1] + sm[1][ch + 1] + sm[2][ch + 1] + sm[3][ch + 1];

    float* Srow = S + ((size_t)b * NVAL + v) * C;
    *reinterpret_cast<float2*>(Srow + ch) = r;
    if (tid == 0) ncnt[b * NVAL + v] = lo2 - lo;
}

// ---------------------------------------------------------------------------
// Kernel 2: pair contributions + finalize (last-block pattern).
// Grid = (8 value-chunks, B batches), 256 threads = 4 waves.
// Wave wid covers v = 1 + 16*chunk + wid + 4*i, i=0..3 (v <= 127).
// Per (wave, v):  part = 0.5|S_v|^2 - S_v.(S_{v+1}+S_{v+2})  (lane partials),
// lane 0 folds in -n_v/2 and the pair count.  Wave-reduce, LDS-combine,
// ONE atomicAdd pair per block.  Last block (counter) computes the loss.
// ---------------------------------------------------------------------------
__global__ void pairsum_finalize_kernel(const float* __restrict__ S,
                                        const int* __restrict__ ncnt,
                                        float* __restrict__ accum,
                                        int* __restrict__ counter,
                                        float* __restrict__ out,
                                        int C) {
    const int chunk = blockIdx.x;   // 0..7
    const int b     = blockIdx.y;
    const int tid   = threadIdx.x;  // 0..255
    const int wid   = tid >> 6;
    const int lane  = tid & 63;

    const float* Sb = S + (size_t)b * NVAL * C;

    float psum = 0.f;   // per-lane partial of the sim-sum
    float csum = 0.f;   // lane-0 only: pair count

    #pragma unroll
    for (int i = 0; i < 4; ++i) {
        const int v = 1 + chunk * 16 + wid + 4 * i;
        if (v >= NVAL) continue;

        const float* Sv = Sb + (size_t)v * C;
        float4 a0 = *reinterpret_cast<const float4*>(Sv + lane * 4);
        float4 a1 = *reinterpret_cast<const float4*>(Sv + 256 + lane * 4);

        float4 w0 = make_float4(0.f, 0.f, 0.f, 0.f);
        float4 w1 = make_float4(0.f, 0.f, 0.f, 0.f);
        if (v + 1 < NVAL) {
            const float* S1 = Sv + C;
            float4 b0 = *reinterpret_cast<const float4*>(S1 + lane * 4);
            float4 b1 = *reinterpret_cast<const float4*>(S1 + 256 + lane * 4);
            w0.x += b0.x; w0.y += b0.y; w0.z += b0.z; w0.w += b0.w;
            w1.x += b1.x; w1.y += b1.y; w1.z += b1.z; w1.w += b1.w;
        }
        if (v + 2 < NVAL) {
            const float* S2 = Sv + 2 * C;
            float4 b0 = *reinterpret_cast<const float4*>(S2 + lane * 4);
            float4 b1 = *reinterpret_cast<const float4*>(S2 + 256 + lane * 4);
            w0.x += b0.x; w0.y += b0.y; w0.z += b0.z; w0.w += b0.w;
            w1.x += b1.x; w1.y += b1.y; w1.z += b1.z; w1.w += b1.w;
        }

        psum += 0.5f * (a0.x*a0.x + a0.y*a0.y + a0.z*a0.z + a0.w*a0.w
                      + a1.x*a1.x + a1.y*a1.y + a1.z*a1.z + a1.w*a1.w)
              - (a0.x*w0.x + a0.y*w0.y + a0.z*w0.z + a0.w*w0.w
               + a1.x*w1.x + a1.y*w1.y + a1.z*w1.z + a1.w*w1.w);

        if (lane == 0) {
            const int nv = ncnt[b * NVAL + v];
            const int n1 = (v + 1 < NVAL) ? ncnt[b * NVAL + v + 1] : 0;
            const int n2 = (v + 2 < NVAL) ? ncnt[b * NVAL + v + 2] : 0;
            psum -= 0.5f * (float)nv;   // summed once after wave-reduce
            csum += 0.5f * (float)(nv * (nv - 1)) + (float)(nv * (n1 + n2));
        }
    }

    #pragma unroll
    for (int off = 32; off > 0; off >>= 1)
        psum += __shfl_down(psum, off, 64);

    __shared__ float sp[4];
    __shared__ float sc[4];
    if (lane == 0) { sp[wid] = psum; sc[wid] = csum; }
    __syncthreads();

    if (tid == 0) {
        const float bp = sp[0] + sp[1] + sp[2] + sp[3];
        const float bc = sc[0] + sc[1] + sc[2] + sc[3];
        atomicAdd(&accum[0], bp);
        atomicAdd(&accum[1], bc);
        __threadfence();
        const int old = atomicAdd(counter, 1);
        const int nblocks = (int)(gridDim.x * gridDim.y);
        if (old == nblocks - 1) {
            const float s = atomicAdd(&accum[0], 0.0f);  // coherent read-back
            const float c = atomicAdd(&accum[1], 0.0f);
            out[0] = 1.0f - s / (c + EPS_DEN);
        }
    }
}

extern "C" void kernel_launch(void* const* d_in, const int* in_sizes, int n_in,
                              void* d_out, int out_size, void* d_ws, size_t ws_size,
                              hipStream_t stream) {
    const float* x       = (const float*)d_in[0];
    const int*   regions = (const int*)d_in[1];

    const int BT = in_sizes[1];              // B*T = 16384
    const int C  = in_sizes[0] / BT;         // 512
    const int T  = 2048;                     // per reference setup
    const int B  = BT / T;                   // 8

    // workspace layout (float units):
    //   [0..1]             accum
    //   [2]                done-counter (int)
    //   [16 .. 16+B*NVAL)  ncnt (int)
    //   [16+B*NVAL .. )    S  (B*NVAL*C floats), 16B-aligned
    float* base    = (float*)d_ws;
    float* accum   = base;
    int*   counter = (int*)(base + 2);
    int*   ncnt    = (int*)(base + 16);
    float* S       = base + 16 + B * NVAL;

    fused_runsum_kernel<<<dim3(NVAL, B), 256, 0, stream>>>(x, regions, S, ncnt,
                                                           accum, counter, T, C);

    pairsum_finalize_kernel<<<dim3(8, B), 256, 0, stream>>>(S, ncnt, accum,
                                                            counter,
                                                            (float*)d_out, C);
}

// Round 11
// 83.091 us; speedup vs baseline: 6.5823x; 1.0147x over previous
//
#include <hip/hip_runtime.h>
#include <math.h>

#define NEIGHBORHOOD 2
#define EPS_NORM 1e-8f
#define EPS_DEN 1e-6f
#define NVAL 128   // region values are in [0, 128)

// ---------------------------------------------------------------------------
// Kernel 1: fused per-run normalized-row sum.
// Block = (region value v, batch b), 256 threads = 4 waves.
// Run bounds via cooperative parallel scan (NOT serial binary search):
// the block reads all T=2048 region ids as coalesced int4 (8 KB, L2-hot);
// each thread counts #(reg<v) and #(reg==v) over its 8 ids; one packed
// shfl-reduce + LDS combine yields lo / lo2.  Replaces a ~22-step dependent
// scalar-load chain (~4400 cy) with one parallel pass.
// Then: wave wid handles rows t = lo+wid, +4, ...; per row compute the norm
// in-register (float4 x2, shfl_xor so all lanes get it) and FMA x_t/||x_t||
// into per-wave accumulators; 4 waves combine via 8 KB LDS; write S, ncnt.
// Block (0,0) zeroes accum + done-counter (kernel boundary orders this
// before kernel 2's atomics).  v==0 runs are padding -> never consumed.
// ---------------------------------------------------------------------------
__global__ void fused_runsum_kernel(const float* __restrict__ x,
                                    const int* __restrict__ regions,
                                    float* __restrict__ S,   // [B][NVAL][C]
                                    int* __restrict__ ncnt,  // [B][NVAL]
                                    float* __restrict__ accum,
                                    int* __restrict__ counter,
                                    int T, int C) {
    const int v    = blockIdx.x;   // 0..127
    const int b    = blockIdx.y;
    const int tid  = threadIdx.x;  // 0..255
    const int wid  = tid >> 6;     // wave 0..3
    const int lane = tid & 63;

    if (v == 0) {                  // padding value: S_0 / n_0 never read
        if (b == 0 && tid == 0) { accum[0] = 0.f; accum[1] = 0.f; *counter = 0; }
        return;
    }

    const int* reg = regions + (size_t)b * T;

    // ---- parallel run-boundary scan: 8 ids per thread, coalesced int4 ----
    const int base_t = tid * 8;    // 256*8 == T == 2048
    int4 r0 = *reinterpret_cast<const int4*>(reg + base_t);
    int4 r1 = *reinterpret_cast<const int4*>(reg + base_t + 4);
    int less = (r0.x < v) + (r0.y < v) + (r0.z < v) + (r0.w < v)
             + (r1.x < v) + (r1.y < v) + (r1.z < v) + (r1.w < v);
    int eq   = (r0.x == v) + (r0.y == v) + (r0.z == v) + (r0.w == v)
             + (r1.x == v) + (r1.y == v) + (r1.z == v) + (r1.w == v);
    int packed = (less << 16) | eq;        // both sums <= 2048, no overflow

    #pragma unroll
    for (int off = 32; off > 0; off >>= 1)
        packed += __shfl_down(packed, off, 64);

    __shared__ int sred[4];
    if (lane == 0) sred[wid] = packed;
    __syncthreads();
    packed = sred[0] + sred[1] + sred[2] + sred[3];

    const int lo  = packed >> 16;
    const int lo2 = lo + (packed & 0xFFFF);

    const float* xb = x + ((size_t)b * T) * C;

    float4 acc0 = make_float4(0.f, 0.f, 0.f, 0.f);
    float4 acc1 = make_float4(0.f, 0.f, 0.f, 0.f);

    for (int t = lo + wid; t < lo2; t += 4) {
        const float* xr = xb + (size_t)t * C;
        float4 a = *reinterpret_cast<const float4*>(xr + lane * 4);
        float4 c = *reinterpret_cast<const float4*>(xr + 256 + lane * 4);
        float ss = a.x*a.x + a.y*a.y + a.z*a.z + a.w*a.w
                 + c.x*c.x + c.y*c.y + c.z*c.z + c.w*c.w;
        #pragma unroll
        for (int off = 32; off > 0; off >>= 1)
            ss += __shfl_xor(ss, off, 64);          // all lanes get the sum
        const float w = 1.0f / fmaxf(sqrtf(ss), EPS_NORM);
        acc0.x = fmaf(w, a.x, acc0.x);
        acc0.y = fmaf(w, a.y, acc0.y);
        acc0.z = fmaf(w, a.z, acc0.z);
        acc0.w = fmaf(w, a.w, acc0.w);
        acc1.x = fmaf(w, c.x, acc1.x);
        acc1.y = fmaf(w, c.y, acc1.y);
        acc1.z = fmaf(w, c.z, acc1.z);
        acc1.w = fmaf(w, c.w, acc1.w);
    }

    // combine the 4 waves' 512-channel accumulators via LDS
    __shared__ float sm[4][512];
    *reinterpret_cast<float4*>(&sm[wid][lane * 4])       = acc0;
    *reinterpret_cast<float4*>(&sm[wid][256 + lane * 4]) = acc1;
    __syncthreads();

    const int ch = tid * 2;
    float2 r;
    r.x = sm[0][ch]     + sm[1][ch]     + sm[2][ch]     + sm[3][ch];
    r.y = sm[0][ch + 1] + sm[1][ch + 1] + sm[2][ch + 1] + sm[3][ch + 1];

    float* Srow = S + ((size_t)b * NVAL + v) * C;
    *reinterpret_cast<float2*>(Srow + ch) = r;
    if (tid == 0) ncnt[b * NVAL + v] = lo2 - lo;
}

// ---------------------------------------------------------------------------
// Kernel 2: pair contributions + finalize (last-block pattern).
// Grid = (8 value-chunks, B batches), 256 threads = 4 waves.
// Wave wid covers v = 1 + 16*chunk + wid + 4*i, i=0..3 (v <= 127).
// Per (wave, v):  part = 0.5|S_v|^2 - S_v.(S_{v+1}+S_{v+2})  (lane partials),
// lane 0 folds in -n_v/2 and the pair count.  Wave-reduce, LDS-combine,
// ONE atomicAdd pair per block.  Last block (counter) computes the loss.
// ---------------------------------------------------------------------------
__global__ void pairsum_finalize_kernel(const float* __restrict__ S,
                                        const int* __restrict__ ncnt,
                                        float* __restrict__ accum,
                                        int* __restrict__ counter,
                                        float* __restrict__ out,
                                        int C) {
    const int chunk = blockIdx.x;   // 0..7
    const int b     = blockIdx.y;
    const int tid   = threadIdx.x;  // 0..255
    const int wid   = tid >> 6;
    const int lane  = tid & 63;

    const float* Sb = S + (size_t)b * NVAL * C;

    float psum = 0.f;   // per-lane partial of the sim-sum
    float csum = 0.f;   // lane-0 only: pair count

    #pragma unroll
    for (int i = 0; i < 4; ++i) {
        const int v = 1 + chunk * 16 + wid + 4 * i;
        if (v >= NVAL) continue;

        const float* Sv = Sb + (size_t)v * C;
        float4 a0 = *reinterpret_cast<const float4*>(Sv + lane * 4);
        float4 a1 = *reinterpret_cast<const float4*>(Sv + 256 + lane * 4);

        float4 w0 = make_float4(0.f, 0.f, 0.f, 0.f);
        float4 w1 = make_float4(0.f, 0.f, 0.f, 0.f);
        if (v + 1 < NVAL) {
            const float* S1 = Sv + C;
            float4 b0 = *reinterpret_cast<const float4*>(S1 + lane * 4);
            float4 b1 = *reinterpret_cast<const float4*>(S1 + 256 + lane * 4);
            w0.x += b0.x; w0.y += b0.y; w0.z += b0.z; w0.w += b0.w;
            w1.x += b1.x; w1.y += b1.y; w1.z += b1.z; w1.w += b1.w;
        }
        if (v + 2 < NVAL) {
            const float* S2 = Sv + 2 * C;
            float4 b0 = *reinterpret_cast<const float4*>(S2 + lane * 4);
            float4 b1 = *reinterpret_cast<const float4*>(S2 + 256 + lane * 4);
            w0.x += b0.x; w0.y += b0.y; w0.z += b0.z; w0.w += b0.w;
            w1.x += b1.x; w1.y += b1.y; w1.z += b1.z; w1.w += b1.w;
        }

        psum += 0.5f * (a0.x*a0.x + a0.y*a0.y + a0.z*a0.z + a0.w*a0.w
                      + a1.x*a1.x + a1.y*a1.y + a1.z*a1.z + a1.w*a1.w)
              - (a0.x*w0.x + a0.y*w0.y + a0.z*w0.z + a0.w*w0.w
               + a1.x*w1.x + a1.y*w1.y + a1.z*w1.z + a1.w*w1.w);

        if (lane == 0) {
            const int nv = ncnt[b * NVAL + v];
            const int n1 = (v + 1 < NVAL) ? ncnt[b * NVAL + v + 1] : 0;
            const int n2 = (v + 2 < NVAL) ? ncnt[b * NVAL + v + 2] : 0;
            psum -= 0.5f * (float)nv;   // summed once after wave-reduce
            csum += 0.5f * (float)(nv * (nv - 1)) + (float)(nv * (n1 + n2));
        }
    }

    #pragma unroll
    for (int off = 32; off > 0; off >>= 1)
        psum += __shfl_down(psum, off, 64);

    __shared__ float sp[4];
    __shared__ float sc[4];
    if (lane == 0) { sp[wid] = psum; sc[wid] = csum; }
    __syncthreads();

    if (tid == 0) {
        const float bp = sp[0] + sp[1] + sp[2] + sp[3];
        const float bc = sc[0] + sc[1] + sc[2] + sc[3];
        atomicAdd(&accum[0], bp);
        atomicAdd(&accum[1], bc);
        __threadfence();
        const int old = atomicAdd(counter, 1);
        const int nblocks = (int)(gridDim.x * gridDim.y);
        if (old == nblocks - 1) {
            const float s = atomicAdd(&accum[0], 0.0f);  // coherent read-back
            const float c = atomicAdd(&accum[1], 0.0f);
            out[0] = 1.0f - s / (c + EPS_DEN);
        }
    }
}

extern "C" void kernel_launch(void* const* d_in, const int* in_sizes, int n_in,
                              void* d_out, int out_size, void* d_ws, size_t ws_size,
                              hipStream_t stream) {
    const float* x       = (const float*)d_in[0];
    const int*   regions = (const int*)d_in[1];

    const int BT = in_sizes[1];              // B*T = 16384
    const int C  = in_sizes[0] / BT;         // 512
    const int T  = 2048;                     // per reference setup
    const int B  = BT / T;                   // 8

    // workspace layout (float units):
    //   [0..1]             accum
    //   [2]                done-counter (int)
    //   [16 .. 16+B*NVAL)  ncnt (int)
    //   [16+B*NVAL .. )    S  (B*NVAL*C floats), 16B-aligned
    float* base    = (float*)d_ws;
    float* accum   = base;
    int*   counter = (int*)(base + 2);
    int*   ncnt    = (int*)(base + 16);
    float* S       = base + 16 + B * NVAL;

    fused_runsum_kernel<<<dim3(NVAL, B), 256, 0, stream>>>(x, regions, S, ncnt,
                                                           accum, counter, T, C);

    pairsum_finalize_kernel<<<dim3(8, B), 256, 0, stream>>>(S, ncnt, accum,
                                                            counter,
                                                            (float*)d_out, C);
}